// Round 6
// baseline (50.391 us; speedup 1.0000x reference)
//
#include <hip/hip_runtime.h>
#include <hip/hip_bf16.h>

// Problem constants (match reference)
#define BB 16384
#define DD 512
#define NCLS 90
#define KC 32
#define BUCKET 512   // max samples per class (mean 182, +24 sigma headroom)
#define NORMB 720    // center-norm blocks in k_prep (2880 rows / 4)
#define CSLOT 32     // 16-sample chunk slots per class (covers n <= 512)
#define NSLOT (NCLS * CSLOT)

typedef __attribute__((ext_vector_type(8))) short short8;   // 8 bf16 (4 VGPRs)
typedef __attribute__((ext_vector_type(4))) float fx4;      // MFMA accumulator

static __device__ __forceinline__ short f2bf(float f) {
    unsigned u = __float_as_uint(f);
    unsigned r = (u + 0x7fffu + ((u >> 16) & 1u)) >> 16;    // RNE
    return (short)r;
}

// ------- kernel 1: prep = center normalize (blocks 0..719) + binning (720..809)
__global__ void k_prep(const float* __restrict__ centers, const int* __restrict__ labels,
                       short* __restrict__ cni, int* __restrict__ idx, int* __restrict__ cnt) {
    if ((int)blockIdx.x < NORMB) {
        // normalize 4 center rows -> bf16 image (one wave per row)
        int row = blockIdx.x * 4 + (threadIdx.x >> 6);      // 0..2879
        int lane = threadIdx.x & 63;
        const float4* p = (const float4*)(centers + (size_t)row * DD);
        float4 a = p[lane * 2];
        float4 b = p[lane * 2 + 1];
        float s = a.x * a.x + a.y * a.y + a.z * a.z + a.w * a.w
                + b.x * b.x + b.y * b.y + b.z * b.z + b.w * b.w;
#pragma unroll
        for (int m = 1; m < 64; m <<= 1) s += __shfl_xor(s, m, 64);
        float sc = rsqrtf(s + 1e-12f);
        short8 v;
        v[0] = f2bf(a.x * sc); v[1] = f2bf(a.y * sc);
        v[2] = f2bf(a.z * sc); v[3] = f2bf(a.w * sc);
        v[4] = f2bf(b.x * sc); v[5] = f2bf(b.y * sc);
        v[6] = f2bf(b.z * sc); v[7] = f2bf(b.w * sc);
        *(short8*)(cni + (size_t)row * DD + lane * 8) = v;
    } else {
        // deterministic ballot-compaction binning, one block per class
        __shared__ int wcnt[4];
        int c = blockIdx.x - NORMB;
        int t = threadIdx.x, w = t >> 6, lane = t & 63;
        int seg = w * (BB / 4);
        int cw = 0;
        for (int j = lane; j < BB / 4; j += 64) cw += (labels[seg + j] == c);
#pragma unroll
        for (int m = 1; m < 64; m <<= 1) cw += __shfl_xor(cw, m, 64);
        if (lane == 0) wcnt[w] = cw;
        __syncthreads();
        int pos = c * BUCKET;
        for (int ww = 0; ww < w; ww++) pos += wcnt[ww];
        for (int j = lane; j < BB / 4; j += 64) {
            bool m = (labels[seg + j] == c);
            unsigned long long mask = __ballot(m);
            if (m) idx[pos + __popcll(mask & ((1ull << lane) - 1ull))] = seg + j;
            pos += __popcll(mask);
        }
        if (t == 0) cnt[c] = wcnt[0] + wcnt[1] + wcnt[2] + wcnt[3];
    }
}

// ------- kernel 2: main — ONE WAVE per 16-sample chunk, zero LDS, no barriers
// grid = 2880 blocks x 64 threads. Slot s = (class c = s>>5, chunk ch = s&31).
// A-fragments: register-direct gathered f32 x (128B-per-row segments), norm
// accumulated in-flight. B-fragments: register-direct bf16 center image
// (L1-resident, read exactly once per chunk). In-register softmax.
__global__ __launch_bounds__(64, 3)
void k_main(const float* __restrict__ x,
            const short* __restrict__ cni,
            const int* __restrict__ cnt,
            const int* __restrict__ idx,
            float* __restrict__ partials) {
    int s = blockIdx.x;
    int c = s >> 5, ch = s & 31;
    int lane = threadIdx.x;                        // 0..63
    int n = cnt[c];
    int base = ch << 4;
    if (base >= n) {                               // inactive slot
        if (lane == 0) partials[s] = 0.f;
        return;
    }

    int r = lane & 15, g4 = lane >> 4;
    int i = base + r; if (i > n - 1) i = n - 1;    // clamped gather
    int g = idx[c * BUCKET + i];
    const float4* xrow = (const float4*)(x + (size_t)g * DD);
    const short8* c0 = (const short8*)(cni + ((size_t)(c * KC) + r) * DD);
    const short8* c1 = (const short8*)(cni + ((size_t)(c * KC) + 16 + r) * DD);

    fx4 acc0 = {0.f, 0.f, 0.f, 0.f};
    fx4 acc1 = {0.f, 0.f, 0.f, 0.f};
    float nrm = 0.f;
#pragma unroll
    for (int ks = 0; ks < 16; ks++) {
        int c16 = ks * 4 + g4;                     // this lane's 8-elem k-chunk
        float4 a = xrow[c16 * 2], b = xrow[c16 * 2 + 1];
        nrm += a.x * a.x + a.y * a.y + a.z * a.z + a.w * a.w
             + b.x * b.x + b.y * b.y + b.z * b.z + b.w * b.w;
        short8 av;
        av[0] = f2bf(a.x); av[1] = f2bf(a.y); av[2] = f2bf(a.z); av[3] = f2bf(a.w);
        av[4] = f2bf(b.x); av[5] = f2bf(b.y); av[6] = f2bf(b.z); av[7] = f2bf(b.w);
        acc0 = __builtin_amdgcn_mfma_f32_16x16x32_bf16(av, c0[c16], acc0, 0, 0, 0);
        acc1 = __builtin_amdgcn_mfma_f32_16x16x32_bf16(av, c1[c16], acc1, 0, 0, 0);
    }
    // full ||x||^2 of row r on every lane of its column group
    nrm += __shfl_xor(nrm, 16, 64);
    nrm += __shfl_xor(nrm, 32, 64);
    float rinv = rsqrtf(nrm + 1e-12f);

    // in-register softmax: D row = g4*4+j (sample), col = lane&15 (center)
    float loss_acc = 0.f;
#pragma unroll
    for (int j = 0; j < 4; j++) {
        int rj = (g4 << 2) + j;
        float xv = __shfl(rinv, rj, 64);           // norm of sample base+rj
        float s0 = acc0[j] * xv;                   // center  lane&15
        float s1 = acc1[j] * xv;                   // center  16+(lane&15)
        float mx = fmaxf(s0, s1);
#pragma unroll
        for (int m = 1; m < 16; m <<= 1) mx = fmaxf(mx, __shfl_xor(mx, m, 64));
        float e0 = expf(s0 - mx), e1 = expf(s1 - mx);
        float Z = e0 + e1;
        float num = e0 * (1.f - s0) + e1 * (1.f - s1);
#pragma unroll
        for (int m = 1; m < 16; m <<= 1) {
            Z   += __shfl_xor(Z, m, 64);
            num += __shfl_xor(num, m, 64);
        }
        if (r == 0 && base + rj < n) loss_acc += num / Z;
    }

#pragma unroll
    for (int m = 1; m < 64; m <<= 1) loss_acc += __shfl_xor(loss_acc, m, 64);
    if (lane == 0) partials[s] = loss_acc;
}

// ------- kernel 3: deterministic final mean over 2880 slot partials ----------
__global__ void k_final(const float* __restrict__ partials, float* __restrict__ out) {
    __shared__ float red[256];
    int t = threadIdx.x;
    float s = 0.f;
    for (int i = t; i < NSLOT; i += 256) s += partials[i];
    red[t] = s;
    __syncthreads();
    for (int h = 128; h > 0; h >>= 1) {
        if (t < h) red[t] += red[t + h];
        __syncthreads();
    }
    if (t == 0) out[0] = red[0] * (1.0f / (float)BB);
}

extern "C" void kernel_launch(void* const* d_in, const int* in_sizes, int n_in,
                              void* d_out, int out_size, void* d_ws, size_t ws_size,
                              hipStream_t stream) {
    const float* x       = (const float*)d_in[0];
    const int*   labels  = (const int*)d_in[1];
    const float* centers = (const float*)d_in[2];
    float* out = (float*)d_out;

    char* ws = (char*)d_ws;
    short* cni      = (short*)(ws + 0);             // 2880*512 bf16 = 2,949,120 B
    int*   idx      = (int*)(ws + 3145728);         // 90*512 ints   =   184,320 B
    int*   cnt      = (int*)(ws + 3407872);         // 90 ints
    float* partials = (float*)(ws + 3408384);       // 2880 floats (all written)

    k_prep<<<NORMB + NCLS, 256, 0, stream>>>(centers, labels, cni, idx, cnt);
    k_main<<<NSLOT, 64, 0, stream>>>(x, cni, cnt, idx, partials);
    k_final<<<1, 256, 0, stream>>>(partials, out);
}

// Round 8
// 44.081 us; speedup vs baseline: 1.1431x; 1.1431x over previous
//
#include <hip/hip_runtime.h>
#include <hip/hip_bf16.h>

// Problem constants (match reference)
#define BB 16384
#define DD 512
#define NCLS 90
#define KC 32
#define BUCKET 512   // max samples per class (mean 182, +24 sigma headroom)
#define NORMB 720    // center-norm blocks in k_prep (2880 rows / 4)
#define CSLOT 32     // 16-sample chunk slots per class (covers n <= 512)
#define NSLOT (NCLS * CSLOT)

typedef __attribute__((ext_vector_type(8))) short short8;   // 8 bf16 (4 VGPRs)
typedef __attribute__((ext_vector_type(4))) float fx4;      // MFMA accumulator

static __device__ __forceinline__ short f2bf(float f) {
    unsigned u = __float_as_uint(f);
    unsigned r = (u + 0x7fffu + ((u >> 16) & 1u)) >> 16;    // RNE
    return (short)r;
}

// ------- kernel 1: prep = center normalize (blocks 0..719) + binning (720..809)
__global__ void k_prep(const float* __restrict__ centers, const int* __restrict__ labels,
                       short* __restrict__ cni, int* __restrict__ idx, int* __restrict__ cnt) {
    if ((int)blockIdx.x < NORMB) {
        // normalize 4 center rows -> bf16 image (one wave per row)
        int row = blockIdx.x * 4 + (threadIdx.x >> 6);      // 0..2879
        int lane = threadIdx.x & 63;
        const float4* p = (const float4*)(centers + (size_t)row * DD);
        float4 a = p[lane * 2];
        float4 b = p[lane * 2 + 1];
        float s = a.x * a.x + a.y * a.y + a.z * a.z + a.w * a.w
                + b.x * b.x + b.y * b.y + b.z * b.z + b.w * b.w;
#pragma unroll
        for (int m = 1; m < 64; m <<= 1) s += __shfl_xor(s, m, 64);
        float sc = rsqrtf(s + 1e-12f);
        short8 v;
        v[0] = f2bf(a.x * sc); v[1] = f2bf(a.y * sc);
        v[2] = f2bf(a.z * sc); v[3] = f2bf(a.w * sc);
        v[4] = f2bf(b.x * sc); v[5] = f2bf(b.y * sc);
        v[6] = f2bf(b.z * sc); v[7] = f2bf(b.w * sc);
        *(short8*)(cni + (size_t)row * DD + lane * 8) = v;
    } else {
        // deterministic ballot-compaction binning, one block per class
        __shared__ int wcnt[4];
        int c = blockIdx.x - NORMB;
        int t = threadIdx.x, w = t >> 6, lane = t & 63;
        int seg = w * (BB / 4);
        int cw = 0;
        for (int j = lane; j < BB / 4; j += 64) cw += (labels[seg + j] == c);
#pragma unroll
        for (int m = 1; m < 64; m <<= 1) cw += __shfl_xor(cw, m, 64);
        if (lane == 0) wcnt[w] = cw;
        __syncthreads();
        int pos = c * BUCKET;
        for (int ww = 0; ww < w; ww++) pos += wcnt[ww];
        for (int j = lane; j < BB / 4; j += 64) {
            bool m = (labels[seg + j] == c);
            unsigned long long mask = __ballot(m);
            if (m) idx[pos + __popcll(mask & ((1ull << lane) - 1ull))] = seg + j;
            pos += __popcll(mask);
        }
        if (t == 0) cnt[c] = wcnt[0] + wcnt[1] + wcnt[2] + wcnt[3];
    }
}

// ------- kernel 2: main — 16-sample chunk per 128-thread block, no c_lds -----
// grid = 2880 slots. Wave w covers all 16 samples x centers w*16..w*16+15.
// A: coalesced f32 gather -> bf16 swizzled x_lds (16 KiB), norms in-flight.
// B: register-direct short8 loads from bf16 center image (64B-line coalesced,
//    L1/L2-resident; pattern numerically validated in round 6).
__global__ __launch_bounds__(128, 4)
void k_main(const float* __restrict__ x,
            const short* __restrict__ cni,
            const int* __restrict__ cnt,
            const int* __restrict__ idx,
            float* __restrict__ partials) {
    __shared__ __align__(16) short x_lds[16 * DD];   // 16 KiB, XOR-swizzled
    __shared__ float S_lds[16][33];
    __shared__ float nrm_lds[16];
    __shared__ float red[2];

    int slot = blockIdx.x;
    int c = slot >> 5, ch = slot & 31;
    int n = cnt[c];
    int base = ch << 4;
    int t = threadIdx.x;
    if (base >= n) {                                 // inactive slot
        if (t == 0) partials[slot] = 0.f;
        return;
    }

    // ---- stage 16 gathered x rows: 8 threads/row, 32B contiguous per lane ----
    int row16 = t >> 3, l8 = t & 7;
    int i = base + row16; if (i > n - 1) i = n - 1;  // clamped gather
    int g = idx[c * BUCKET + i];
    const float4* xrow = (const float4*)(x + (size_t)g * DD);
    float nrm = 0.f;
#pragma unroll
    for (int j = 0; j < 8; j++) {
        int cc = l8 + 8 * j;                          // 16B bf16 chunk 0..63
        float4 a = xrow[cc * 2], b = xrow[cc * 2 + 1];
        nrm += a.x * a.x + a.y * a.y + a.z * a.z + a.w * a.w
             + b.x * b.x + b.y * b.y + b.z * b.z + b.w * b.w;
        short8 v;
        v[0] = f2bf(a.x); v[1] = f2bf(a.y); v[2] = f2bf(a.z); v[3] = f2bf(a.w);
        v[4] = f2bf(b.x); v[5] = f2bf(b.y); v[6] = f2bf(b.z); v[7] = f2bf(b.w);
        *(short8*)&x_lds[row16 * DD + ((cc ^ (row16 & 7)) << 3)] = v;
    }
#pragma unroll
    for (int m = 1; m < 8; m <<= 1) nrm += __shfl_xor(nrm, m, 64);
    if (l8 == 0) nrm_lds[row16] = nrm;
    __syncthreads();

    // ---- MFMA: wave w = centers w*16..+15 vs samples 0..15 ----
    int w = t >> 6, lane = t & 63;
    int r = lane & 15, g4 = lane >> 4;
    const short8* cp = (const short8*)(cni + ((size_t)(c * KC) + w * 16 + r) * DD);
    fx4 acc = {0.f, 0.f, 0.f, 0.f};
#pragma unroll
    for (int ks = 0; ks < 16; ks++) {
        int c16 = ks * 4 + g4;                        // this lane's 8-elem chunk
        short8 av = *(const short8*)&x_lds[r * DD + ((c16 ^ (r & 7)) << 3)];
        acc = __builtin_amdgcn_mfma_f32_16x16x32_bf16(av, cp[c16], acc, 0, 0, 0);
    }
#pragma unroll
    for (int j = 0; j < 4; j++)                       // D: row=(g4*4+j)=sample
        S_lds[(g4 << 2) + j][w * 16 + r] = acc[j];    //    col=lane&15=center
    __syncthreads();

    // ---- softmax over K=32 + per-sample loss; 8 threads per row ----
    float loss = 0.f;
    {
        float xv = rsqrtf(nrm_lds[row16] + 1e-12f);
        int q4 = l8 << 2;
        float s0 = S_lds[row16][q4 + 0] * xv;
        float s1 = S_lds[row16][q4 + 1] * xv;
        float s2 = S_lds[row16][q4 + 2] * xv;
        float s3 = S_lds[row16][q4 + 3] * xv;
        float mx = fmaxf(fmaxf(s0, s1), fmaxf(s2, s3));
#pragma unroll
        for (int m = 1; m < 8; m <<= 1) mx = fmaxf(mx, __shfl_xor(mx, m, 64));
        float e0 = expf(s0 - mx), e1 = expf(s1 - mx);
        float e2 = expf(s2 - mx), e3 = expf(s3 - mx);
        float Z = e0 + e1 + e2 + e3;
        float num = e0 * (1.f - s0) + e1 * (1.f - s1)
                  + e2 * (1.f - s2) + e3 * (1.f - s3);
#pragma unroll
        for (int m = 1; m < 8; m <<= 1) {
            Z   += __shfl_xor(Z, m, 64);
            num += __shfl_xor(num, m, 64);
        }
        if (l8 == 0 && base + row16 < n) loss = num / Z;
    }

    // ---- block partial (fixed order) ----
#pragma unroll
    for (int m = 1; m < 64; m <<= 1) loss += __shfl_xor(loss, m, 64);
    if (lane == 0) red[w] = loss;
    __syncthreads();
    if (t == 0) partials[slot] = red[0] + red[1];
}

// ------- kernel 3: deterministic final mean over 2880 slot partials ----------
__global__ void k_final(const float* __restrict__ partials, float* __restrict__ out) {
    __shared__ float red[256];
    int t = threadIdx.x;
    float s = 0.f;
    for (int i = t; i < NSLOT; i += 256) s += partials[i];
    red[t] = s;
    __syncthreads();
    for (int h = 128; h > 0; h >>= 1) {
        if (t < h) red[t] += red[t + h];
        __syncthreads();
    }
    if (t == 0) out[0] = red[0] * (1.0f / (float)BB);
}

extern "C" void kernel_launch(void* const* d_in, const int* in_sizes, int n_in,
                              void* d_out, int out_size, void* d_ws, size_t ws_size,
                              hipStream_t stream) {
    const float* x       = (const float*)d_in[0];
    const int*   labels  = (const int*)d_in[1];
    const float* centers = (const float*)d_in[2];
    float* out = (float*)d_out;

    char* ws = (char*)d_ws;
    short* cni      = (short*)(ws + 0);             // 2880*512 bf16 = 2,949,120 B
    int*   idx      = (int*)(ws + 3145728);         // 90*512 ints   =   184,320 B
    int*   cnt      = (int*)(ws + 3407872);         // 90 ints
    float* partials = (float*)(ws + 3408384);       // 2880 floats (all written)

    k_prep<<<NORMB + NCLS, 256, 0, stream>>>(centers, labels, cni, idx, cnt);
    k_main<<<NSLOT, 128, 0, stream>>>(x, cni, cnt, idx, partials);
    k_final<<<1, 256, 0, stream>>>(partials, out);
}

// Round 9
// 28.690 us; speedup vs baseline: 1.7564x; 1.5365x over previous
//
#include <hip/hip_runtime.h>
#include <hip/hip_bf16.h>

// Problem constants (match reference)
#define BB 16384
#define DD 512
#define NCLS 90
#define KC 32
#define BUCKET 512   // max samples per class (mean 182, +24 sigma headroom)
#define PRB 180      // center-norm blocks in k_prep (2880 rows / 16 waves)

typedef __attribute__((ext_vector_type(8))) short short8;   // 8 bf16 (4 VGPRs)
typedef __attribute__((ext_vector_type(4))) float fx4;      // MFMA accumulator

static __device__ __forceinline__ short f2bf(float f) {
    unsigned u = __float_as_uint(f);
    unsigned r = (u + 0x7fffu + ((u >> 16) & 1u)) >> 16;    // RNE
    return (short)r;
}

static __device__ __forceinline__ void gload_lds16(const void* g, void* l) {
    __builtin_amdgcn_global_load_lds(
        (const __attribute__((address_space(1))) void*)g,
        (__attribute__((address_space(3))) void*)l, 16, 0, 0);
}

// ------- kernel 1: prep (1024 thr) = center norm (0..179) + LDS binning (180..269)
__global__ __launch_bounds__(1024)
void k_prep(const float* __restrict__ centers, const int* __restrict__ labels,
            short* __restrict__ cni, int* __restrict__ idx, int* __restrict__ cnt) {
    __shared__ int lab[BB];       // 64 KiB: label cache for binning blocks
    __shared__ int wcnt[16];

    int t = threadIdx.x, w = t >> 6, lane = t & 63;

    if ((int)blockIdx.x < PRB) {
        // ---- normalize 16 center rows -> bf16 image (one wave per row) ----
        int row = blockIdx.x * 16 + w;                  // 0..2879
        const float4* p = (const float4*)(centers + (size_t)row * DD);
        float4 a = p[lane * 2];
        float4 b = p[lane * 2 + 1];
        float s = a.x * a.x + a.y * a.y + a.z * a.z + a.w * a.w
                + b.x * b.x + b.y * b.y + b.z * b.z + b.w * b.w;
#pragma unroll
        for (int m = 1; m < 64; m <<= 1) s += __shfl_xor(s, m, 64);
        float sc = rsqrtf(s + 1e-12f);
        short8 v;
        v[0] = f2bf(a.x * sc); v[1] = f2bf(a.y * sc);
        v[2] = f2bf(a.z * sc); v[3] = f2bf(a.w * sc);
        v[4] = f2bf(b.x * sc); v[5] = f2bf(b.y * sc);
        v[6] = f2bf(b.z * sc); v[7] = f2bf(b.w * sc);
        *(short8*)(cni + (size_t)row * DD + lane * 8) = v;
    } else {
        // ---- deterministic binning from LDS label cache, one block/class ----
        int c = blockIdx.x - PRB;
        for (int j = t; j < BB / 4; j += 1024)          // coalesced int4 load
            ((int4*)lab)[j] = ((const int4*)labels)[j];
        __syncthreads();

        int seg4 = w * (BB / 4 / 16);                   // 256 int4s per wave
        // pass 1: count (4 int4 iters per lane)
        int cw = 0;
#pragma unroll
        for (int jj = 0; jj < 4; jj++) {
            int4 v = ((int4*)lab)[seg4 + jj * 64 + lane];
            cw += (v.x == c) + (v.y == c) + (v.z == c) + (v.w == c);
        }
#pragma unroll
        for (int m = 1; m < 64; m <<= 1) cw += __shfl_xor(cw, m, 64);
        if (lane == 0) wcnt[w] = cw;
        __syncthreads();
        int pos = c * BUCKET;
        for (int ww = 0; ww < w; ww++) pos += wcnt[ww];
        // pass 2: ballot-compaction emit (fixed (jj,e,lane) order -> deterministic)
#pragma unroll
        for (int jj = 0; jj < 4; jj++) {
            int4 v = ((int4*)lab)[seg4 + jj * 64 + lane];
            int gbase = (seg4 + jj * 64 + lane) * 4;
            {
                bool m = (v.x == c); unsigned long long k = __ballot(m);
                if (m) idx[pos + __popcll(k & ((1ull << lane) - 1ull))] = gbase + 0;
                pos += __popcll(k);
            }
            {
                bool m = (v.y == c); unsigned long long k = __ballot(m);
                if (m) idx[pos + __popcll(k & ((1ull << lane) - 1ull))] = gbase + 1;
                pos += __popcll(k);
            }
            {
                bool m = (v.z == c); unsigned long long k = __ballot(m);
                if (m) idx[pos + __popcll(k & ((1ull << lane) - 1ull))] = gbase + 2;
                pos += __popcll(k);
            }
            {
                bool m = (v.w == c); unsigned long long k = __ballot(m);
                if (m) idx[pos + __popcll(k & ((1ull << lane) - 1ull))] = gbase + 3;
                pos += __popcll(k);
            }
        }
        if (t == 0) {
            int s = 0;
#pragma unroll
            for (int i = 0; i < 16; i++) s += wcnt[i];
            cnt[c] = s;
        }
    }
}

// ------- kernel 2: main — bucketed MFMA + softmax (R3-verbatim, proven) ------
__launch_bounds__(256, 2)
__global__ void k_main(const float* __restrict__ x,
                       const short* __restrict__ cni,
                       const int* __restrict__ cnt,
                       const int* __restrict__ idx,
                       float* __restrict__ partials) {
    __shared__ __align__(16) short c_lds[KC * DD];   // 32 KiB bf16, XOR-swizzled
    __shared__ __align__(16) short x_lds[32 * DD];   // 32 KiB bf16, XOR-swizzled
    __shared__ float S_lds[32][33];
    __shared__ float xinv[32];
    __shared__ float red[256];

    int c = blockIdx.x >> 3;
    int p = blockIdx.x & 7;
    int n = cnt[c];
    int nch = (n + 31) >> 5;
    int t = threadIdx.x, w = t >> 6, lane = t & 63;
    float loss_acc = 0.f;

    if (p < nch) {
        const short* cbase = cni + (size_t)c * KC * DD;
#pragma unroll
        for (int it = 0; it < 8; it++) {
            int q = t + 256 * it;                 // 16B chunk 0..2047, linear LDS
            int drow = q >> 6, cc = q & 63;
            int scc = cc ^ (drow & 7);
            gload_lds16(cbase + drow * DD + scc * 8, &c_lds[q * 8]);
        }

        int base = c * BUCKET;
        int mrow = ((w & 1) << 4) + (lane & 15);
        int nrow = ((w >> 1) << 4) + (lane & 15);
        int row8 = t >> 3, l8 = t & 7;            // 8 threads per sample row

        for (int ch = p; ch < nch; ch += 8) {
            int off = ch << 5;
            int rem = n - off;                    // > 0

            // ---- gather raw f32 x row, accumulate sq-norm, cvt->bf16 LDS ----
            {
                int r = (row8 < rem) ? row8 : (rem - 1);
                int g = idx[base + off + r];
                const float4* src = (const float4*)(x + (size_t)g * DD);
                float nrm = 0.f;
#pragma unroll
                for (int jj = 0; jj < 8; jj++) {
                    int cc = l8 + 8 * jj;          // 16B bf16 chunk 0..63
                    float4 a = src[cc * 2], b = src[cc * 2 + 1];
                    nrm += a.x * a.x + a.y * a.y + a.z * a.z + a.w * a.w
                         + b.x * b.x + b.y * b.y + b.z * b.z + b.w * b.w;
                    short8 v;
                    v[0] = f2bf(a.x); v[1] = f2bf(a.y); v[2] = f2bf(a.z); v[3] = f2bf(a.w);
                    v[4] = f2bf(b.x); v[5] = f2bf(b.y); v[6] = f2bf(b.z); v[7] = f2bf(b.w);
                    *(short8*)&x_lds[row8 * DD + ((cc ^ (row8 & 7)) << 3)] = v;
                }
#pragma unroll
                for (int m = 1; m < 8; m <<= 1) nrm += __shfl_xor(nrm, m, 64);
                if (l8 == 0) xinv[row8] = rsqrtf(nrm + 1e-12f);
            }
            __syncthreads();

            // ---- MFMA: S[32 samples][32 k] in 4 wave-quadrants ----
            fx4 acc = {0.f, 0.f, 0.f, 0.f};
#pragma unroll
            for (int ks = 0; ks < 16; ks++) {
                int c16a = ks * 4 + (lane >> 4);
                short8 av = *(const short8*)&x_lds[mrow * DD + ((c16a ^ (mrow & 7)) << 3)];
                short8 bv = *(const short8*)&c_lds[nrow * DD + ((c16a ^ (nrow & 7)) << 3)];
                acc = __builtin_amdgcn_mfma_f32_16x16x32_bf16(av, bv, acc, 0, 0, 0);
            }
#pragma unroll
            for (int j = 0; j < 4; j++) {
                int r = ((w & 1) << 4) + ((lane >> 4) << 2) + j;   // C/D row
                int col = ((w >> 1) << 4) + (lane & 15);           // C/D col
                S_lds[r][col] = acc[j];
            }
            __syncthreads();

            // ---- softmax over K=32 + per-sample loss; 8 threads per row ----
            {
                float xv = xinv[row8];
                int q4 = l8 << 2;
                float s0 = S_lds[row8][q4 + 0] * xv;
                float s1 = S_lds[row8][q4 + 1] * xv;
                float s2 = S_lds[row8][q4 + 2] * xv;
                float s3 = S_lds[row8][q4 + 3] * xv;
                float mx = fmaxf(fmaxf(s0, s1), fmaxf(s2, s3));
#pragma unroll
                for (int m = 1; m < 8; m <<= 1) mx = fmaxf(mx, __shfl_xor(mx, m, 64));
                float e0 = expf(s0 - mx), e1 = expf(s1 - mx);
                float e2 = expf(s2 - mx), e3 = expf(s3 - mx);
                float Z = e0 + e1 + e2 + e3;
                float num = e0 * (1.f - s0) + e1 * (1.f - s1)
                          + e2 * (1.f - s2) + e3 * (1.f - s3);
#pragma unroll
                for (int m = 1; m < 8; m <<= 1) {
                    Z += __shfl_xor(Z, m, 64);
                    num += __shfl_xor(num, m, 64);
                }
                if (l8 == 0 && row8 < rem) loss_acc += num / Z;
            }
            __syncthreads();   // protect x_lds/S_lds before next chunk
        }
    }

    // ---- per-block fixed-order partial reduction ----
    red[t] = loss_acc;
    __syncthreads();
    for (int h = 128; h > 0; h >>= 1) {
        if (t < h) red[t] += red[t + h];
        __syncthreads();
    }
    if (t == 0) partials[blockIdx.x] = red[0];
}

// ------- kernel 3: deterministic final mean over 720 block partials ----------
__global__ void k_final(const float* __restrict__ partials, float* __restrict__ out) {
    __shared__ float red[256];
    int t = threadIdx.x;
    float s = 0.f;
    for (int i = t; i < NCLS * 8; i += 256) s += partials[i];
    red[t] = s;
    __syncthreads();
    for (int h = 128; h > 0; h >>= 1) {
        if (t < h) red[t] += red[t + h];
        __syncthreads();
    }
    if (t == 0) out[0] = red[0] * (1.0f / (float)BB);
}

extern "C" void kernel_launch(void* const* d_in, const int* in_sizes, int n_in,
                              void* d_out, int out_size, void* d_ws, size_t ws_size,
                              hipStream_t stream) {
    const float* x       = (const float*)d_in[0];
    const int*   labels  = (const int*)d_in[1];
    const float* centers = (const float*)d_in[2];
    float* out = (float*)d_out;

    char* ws = (char*)d_ws;
    short* cni      = (short*)(ws + 0);             // 2880*512 bf16 = 2,949,120 B
    int*   idx      = (int*)(ws + 3145728);         // 90*512 ints   =   184,320 B
    int*   cnt      = (int*)(ws + 3407872);         // 90 ints
    float* partials = (float*)(ws + 3473408);       // 720 floats

    k_prep<<<PRB + NCLS, 1024, 0, stream>>>(centers, labels, cni, idx, cnt);
    k_main<<<NCLS * 8, 256, 0, stream>>>(x, cni, cnt, idx, partials);
    k_final<<<1, 256, 0, stream>>>(partials, out);
}